// Round 14
// baseline (51.226 us; speedup 1.0000x reference)
//
#include <hip/hip_runtime.h>
#include <hip/hip_bf16.h>
#include <stdint.h>

// Problem constants (B=8, S=512, D=1024)
constexpr int N_TOK  = 4096;   // B*S
constexpr int D_DIM  = 1024;
constexpr int MASK_ID_V = 8192;

// Fast path: 128x128 tiles, 1024 blocks (~4/CU co-resident), 4 waves (2x2 of
// 64x64), fp8 MX 32x32x64, BK=128/iter (8 iters), 32 KB single-buffer LDS,
// FRAGMENT-ORDER layout (contiguous 1KB chunks, conflict-free linear reads)
constexpr int BMX  = 128;
constexpr int KIT  = D_DIM / 128;    // 8 K-iters
constexpr int NSL3 = N_TOK / BMX;    // 32 col slices
constexpr int NPART = NSL3 * 2;      // 64 partials/row (2 wc-waves per slice)

constexpr float SCALE   = 64.0f;     // pre-scale into e4m3 normal range
constexpr float INVSC2  = 1.0f / (SCALE * SCALE);

// Fallback tiling (used only if ws too small)
constexpr int BM = 128, BN = 128, BK = 64;
constexpr int KST = D_DIM / BK;
constexpr int NSLICE_FB = 8;
constexpr int SLICE_W   = N_TOK / NSLICE_FB;
constexpr int CTS       = SLICE_W / BN;
constexpr int LDW       = BK + 8;
constexpr int NPART_FB  = NSLICE_FB * 2;

constexpr int FIN_BLOCKS = 256;

typedef __attribute__((ext_vector_type(4)))  float f32x4;
typedef __attribute__((ext_vector_type(16))) float f32x16;
typedef __attribute__((ext_vector_type(8)))  short bf16x8;
typedef __attribute__((ext_vector_type(8)))  int   i32x8;

__device__ __forceinline__ uint32_t pk2bf(float lo, float hi) {
    union { float f; uint32_t u; } a, b;
    a.f = lo; b.f = hi;
    uint32_t ua = (a.u + 0x7fffu + ((a.u >> 16) & 1u)) >> 16;
    uint32_t ub = (b.u + 0x7fffu + ((b.u >> 16) & 1u)) >> 16;
    return ua | (ub << 16);
}

__device__ __forceinline__ void async16(void* lds, const void* g) {
    __builtin_amdgcn_global_load_lds(
        (const __attribute__((address_space(1))) uint32_t*)g,
        (__attribute__((address_space(3))) uint32_t*)lds,
        16, 0, 0);
}

#define BAR do { __builtin_amdgcn_s_barrier(); __builtin_amdgcn_sched_barrier(0); } while (0)

// ---------------------------------------------------------------------------
// Pass 1: fp32 -> fp8 e4m3 pre-convert, output in MFMA-FRAGMENT-CHUNK order
// (r13-verified). Chunk id = (R*8 + kt)*4 + ks*2 + j (R = row/32,
// kt = col/128, ks = (col>>6)&1, j = (col>>4)&1); within a 1KB chunk,
// lane = (col>>5 &1)*32 + (row&31) holds 16 bytes.
// ---------------------------------------------------------------------------
__device__ __forceinline__ uint pk4fp8(float4 v) {
    int w = __builtin_amdgcn_cvt_pk_fp8_f32(v.x * SCALE, v.y * SCALE, 0, false);
    w = __builtin_amdgcn_cvt_pk_fp8_f32(v.z * SCALE, v.w * SCALE, w, true);
    return (uint)w;
}

__global__ __launch_bounds__(256) void conv_fp8_frag(
    const float* __restrict__ x, const float* __restrict__ e,
    unsigned char* __restrict__ xb8, unsigned char* __restrict__ eb8)
{
    constexpr int NT = N_TOK * 64;        // tasks: (row, 16-float chunk)
    const int t0 = blockIdx.x * blockDim.x + threadIdx.x;
    const int stride = gridDim.x * blockDim.x;
    for (int t = t0; t < NT; t += stride) {
        const int r   = t >> 6;           // source row (reads coalesced)
        const int c16 = t & 63;           // 16-float chunk within row
        const int R   = r >> 5;
        const int kt  = c16 >> 3;
        const int ks  = (c16 >> 2) & 1;
        const int lg  = (c16 >> 1) & 1;
        const int j   = c16 & 1;
        const int lane = lg * 32 + (r & 31);
        const size_t off =
            (((size_t)(R * 8 + kt) * 4 + ks * 2 + j) * 64 + lane) * 16;

        const float* sx = x + (size_t)r * D_DIM + c16 * 16;
        uint4 o;
        o.x = pk4fp8(*(const float4*)(sx));
        o.y = pk4fp8(*(const float4*)(sx + 4));
        o.z = pk4fp8(*(const float4*)(sx + 8));
        o.w = pk4fp8(*(const float4*)(sx + 12));
        *(uint4*)(xb8 + off) = o;

        const float* se = e + (size_t)r * D_DIM + c16 * 16;
        uint4 q;
        q.x = pk4fp8(*(const float4*)(se));
        q.y = pk4fp8(*(const float4*)(se + 4));
        q.z = pk4fp8(*(const float4*)(se + 8));
        q.w = pk4fp8(*(const float4*)(se + 12));
        *(uint4*)(eb8 + off) = q;
    }
}

// ---------------------------------------------------------------------------
// Pass 2: fp8 MX GEMM — 128^2 tile, 4 waves, single-buffer, frag-order LDS,
// ~4 co-resident blocks/CU for cross-block latency hiding (m114/m148)
// ---------------------------------------------------------------------------
__device__ __forceinline__ i32x8 ld_frag(const unsigned char* base) {
    uint4 u = *(const uint4*)(base);          // j=0 chunk
    uint4 v = *(const uint4*)(base + 1024);   // j=1 chunk
    i32x8 r = { (int)u.x, (int)u.y, (int)u.z, (int)u.w,
                (int)v.x, (int)v.y, (int)v.z, (int)v.w };
    return r;
}

#define MFMA8(A_, B_, C_) __builtin_amdgcn_mfma_scale_f32_32x32x64_f8f6f4( \
    A_, B_, C_, 0, 0, 0, 127, 0, 127)

__global__ __launch_bounds__(256, 3) void nce_gemm_mx(
    const unsigned char* __restrict__ xb8,   // frag-ordered fp8 keys (x*64)
    const unsigned char* __restrict__ eb8,   // frag-ordered fp8 queries
    float* __restrict__ numer,
    float* __restrict__ pm,
    float* __restrict__ ps)
{
    __shared__ unsigned char As[16384];   // 16 chunks x 1KB, single buffer
    __shared__ unsigned char Bs[16384];   // total 32 KB

    // Bijective XCD swizzle (1024 blocks): each XCD -> 4 col slices
    const int bid  = blockIdx.x;
    const int sw_  = (bid & 7) * 128 + (bid >> 3);
    const int rb   = sw_ & 31;
    const int cs   = sw_ >> 5;
    const int row0 = rb * BMX;
    const int col0 = cs * BMX;

    const int tid  = threadIdx.x;
    const int lane = tid & 63;
    const int wid  = tid >> 6;         // 0..3
    const int wr   = wid >> 1;         // 0..1 (M-waves, 64 rows)
    const int wc   = wid & 1;          // 0..1 (N-waves, 64 cols)
    const int l31  = lane & 31;
    const int lg   = lane >> 5;        // 0..1

    // Staging: 16 chunks of 1KB per matrix per K-iter; wave wid covers
    // chunks c = wid*4 .. wid*4+3. Chunk c = R_loc*4 + q (q = ks*2+j);
    // source chunk id = ((rb*4 + R_loc)*8 + kt)*4 + q. Fully coalesced.
    const int cch   = wid * 4;                 // first chunk this wave
    const int R_loc = cch >> 2;                // == wid
    const unsigned char* sA = eb8 +
        ((size_t)((rb * 4 + R_loc) * 8) * 4) * 1024 + (size_t)lane * 16;
    const unsigned char* sB = xb8 +
        ((size_t)((cs * 4 + R_loc) * 8) * 4) * 1024 + (size_t)lane * 16;
    unsigned char* dA = As + cch * 1024;       // wave-uniform linear dest
    unsigned char* dB = Bs + cch * 1024;

    // Frag read bases (linear, conflict-free): chunk (wr*2+m)*4 + ks*2 + j
    const int aBase = wr * 8192 + lane * 16;   // m -> +4096, ks -> +2048
    const int bBase = wc * 8192 + lane * 16;

    f32x16 acc00, acc01, acc10, acc11;
#pragma unroll
    for (int i = 0; i < 16; ++i) { acc00[i] = 0.f; acc01[i] = 0.f; acc10[i] = 0.f; acc11[i] = 0.f; }

#pragma unroll 1
    for (int kt = 0; kt < KIT; ++kt) {
        BAR;   // previous iteration's readers done with the buffer
        const size_t adv = (size_t)kt * 4096;  // kt advance = 4 chunks
#pragma unroll
        for (int q = 0; q < 4; ++q) {
            async16(dA + q * 1024, sA + adv + q * 1024);
            async16(dB + q * 1024, sB + adv + q * 1024);
        }
        asm volatile("s_waitcnt vmcnt(0)" ::: "memory");
        BAR;   // whole K-tile resident

#pragma unroll
        for (int ks = 0; ks < 2; ++ks) {
            i32x8 a0 = ld_frag(As + aBase + ks * 2048);
            i32x8 a1 = ld_frag(As + aBase + 4096 + ks * 2048);
            i32x8 b0 = ld_frag(Bs + bBase + ks * 2048);
            i32x8 b1 = ld_frag(Bs + bBase + 4096 + ks * 2048);
            __builtin_amdgcn_s_setprio(1);
            acc00 = MFMA8(a0, b0, acc00);
            acc01 = MFMA8(a0, b1, acc01);
            acc10 = MFMA8(a1, b0, acc10);
            acc11 = MFMA8(a1, b1, acc11);
            __builtin_amdgcn_s_setprio(0);
        }
    }

    // Epilogue (r8/r13-verified). 32x32 C/D: col = lane&31,
    // row = (reg&3)+8*(reg>>2)+4*lg; fr adds 32 rows.
    const int c0g = col0 + wc * 64 + l31;
    const int c1g = c0g + 32;

#pragma unroll
    for (int reg = 0; reg < 16; ++reg) {
        const int rif = (reg & 3) + 8 * (reg >> 2) + 4 * lg;
#pragma unroll
        for (int fr = 0; fr < 2; ++fr) {
            const int row_g = row0 + wr * 64 + fr * 32 + rif;
            const float v0 = (fr ? acc10[reg] : acc00[reg]) * INVSC2;
            const float v1 = (fr ? acc11[reg] : acc01[reg]) * INVSC2;
            if (row_g == c0g) numer[row_g] = v0;
            if (row_g == c1g) numer[row_g] = v1;
            float m = fmaxf(v0, v1);
#pragma unroll
            for (int off = 1; off <= 16; off <<= 1)
                m = fmaxf(m, __shfl_xor(m, off, 64));
            float s = __expf(v0 - m) + __expf(v1 - m);
#pragma unroll
            for (int off = 1; off <= 16; off <<= 1)
                s += __shfl_xor(s, off, 64);
            if (l31 == 0) {
                pm[row_g * NPART + cs * 2 + wc] = m;
                ps[row_g * NPART + cs * 2 + wc] = s;
            }
        }
    }
}

// ---------------------------------------------------------------------------
// Pass 3a: one WAVE per row — coalesced partial combine + masked row loss
// ---------------------------------------------------------------------------
__global__ __launch_bounds__(256) void nce_finish_a(
    const int* __restrict__ tgt,
    const float* __restrict__ numer,
    const float* __restrict__ pm,
    const float* __restrict__ ps,
    float* __restrict__ bl_loss,
    float* __restrict__ bl_cnt,
    int npart)
{
    const int tid  = threadIdx.x;
    const int lane = tid & 63;
    const int wv   = tid >> 6;
    const int waves_total = gridDim.x * 4;

    float loss = 0.f, cnt = 0.f;

    for (int row = blockIdx.x * 4 + wv; row < N_TOK; row += waves_total) {
        if (tgt[row] != MASK_ID_V) continue;
        float pmv = -3.0e38f, psv = 0.f;
        if (lane < npart) {
            pmv = pm[row * npart + lane];
            psv = ps[row * npart + lane];
        }
        float m = pmv;
#pragma unroll
        for (int off = 32; off; off >>= 1) m = fmaxf(m, __shfl_xor(m, off, 64));
        float sv = psv * __expf(pmv - m);
#pragma unroll
        for (int off = 32; off; off >>= 1) sv += __shfl_xor(sv, off, 64);
        if (lane == 0) {
            loss += numer[row] - (m + __logf(sv));
            cnt  += 1.f;
        }
    }

    __shared__ float sl[4], sc[4];
    if (lane == 0) { sl[wv] = loss; sc[wv] = cnt; }
    __syncthreads();
    if (tid == 0) {
        bl_loss[blockIdx.x] = sl[0] + sl[1] + sl[2] + sl[3];
        bl_cnt[blockIdx.x]  = sc[0] + sc[1] + sc[2] + sc[3];
    }
}

__global__ __launch_bounds__(256) void nce_finish_b(
    const float* __restrict__ bl_loss,
    const float* __restrict__ bl_cnt,
    float* __restrict__ out, int nblk)
{
    const int tid = threadIdx.x;
    float l = 0.f, c = 0.f;
    for (int i = tid; i < nblk; i += 256) { l += bl_loss[i]; c += bl_cnt[i]; }
    __shared__ float sl[256], sc[256];
    sl[tid] = l; sc[tid] = c;
    __syncthreads();
    for (int off = 128; off; off >>= 1) {
        if (tid < off) { sl[tid] += sl[tid + off]; sc[tid] += sc[tid + off]; }
        __syncthreads();
    }
    if (tid == 0) out[0] = -(sl[0] / sc[0]);
}

// ---------------------------------------------------------------------------
// Fallback (bf16 on-the-fly convert) — only if ws too small
// ---------------------------------------------------------------------------
__global__ __launch_bounds__(256, 2) void nce_gemm_fb(
    const float* __restrict__ x, const float* __restrict__ emb,
    float* __restrict__ numer, float* __restrict__ pm, float* __restrict__ ps)
{
    __shared__ ushort At[BM][LDW];
    __shared__ ushort Bt[BN][LDW];

    const int rb = blockIdx.x, cs = blockIdx.y;
    const int row0 = rb * BM, col0 = cs * SLICE_W;
    const int tid = threadIdx.x, lane = tid & 63, wid = tid >> 6;
    const int wr = wid >> 1, wc = wid & 1, l15 = lane & 15, lhi = lane >> 4;

    float m_run[16], s_run[16];
#pragma unroll
    for (int i = 0; i < 16; ++i) { m_run[i] = -3.0e38f; s_run[i] = 0.0f; }

    for (int ct = 0; ct < CTS; ++ct) {
        const int colt0 = col0 + ct * BN;
        f32x4 acc[4][4];
#pragma unroll
        for (int a = 0; a < 4; ++a)
#pragma unroll
            for (int b = 0; b < 4; ++b) acc[a][b] = f32x4{0.f,0.f,0.f,0.f};

#pragma unroll 1
        for (int kt = 0; kt < KST; ++kt) {
            __syncthreads();
#pragma unroll
            for (int i = 0; i < 4; ++i) {
                const int chunk = tid + i * 256;
                const int r = chunk >> 3, c8 = (chunk & 7) << 3;
                const float* ga = emb + (size_t)(row0 + r) * D_DIM + kt * BK + c8;
                float4 a0 = *(const float4*)(ga); float4 a1 = *(const float4*)(ga + 4);
                uint4 pa;
                pa.x = pk2bf(a0.x, a0.y); pa.y = pk2bf(a0.z, a0.w);
                pa.z = pk2bf(a1.x, a1.y); pa.w = pk2bf(a1.z, a1.w);
                *(uint4*)&At[r][c8] = pa;
                const float* gb = x + (size_t)(colt0 + r) * D_DIM + kt * BK + c8;
                float4 b0 = *(const float4*)(gb); float4 b1 = *(const float4*)(gb + 4);
                uint4 pb;
                pb.x = pk2bf(b0.x, b0.y); pb.y = pk2bf(b0.z, b0.w);
                pb.z = pk2bf(b1.x, b1.y); pb.w = pk2bf(b1.z, b1.w);
                *(uint4*)&Bt[r][c8] = pb;
            }
            __syncthreads();
#pragma unroll
            for (int kp = 0; kp < 2; ++kp) {
                const int ko = kp * 32 + lhi * 8;
                bf16x8 af[4], bfr[4];
#pragma unroll
                for (int mi = 0; mi < 4; ++mi)
                    af[mi] = *(const bf16x8*)&At[wr*64 + mi*16 + l15][ko];
#pragma unroll
                for (int ni = 0; ni < 4; ++ni)
                    bfr[ni] = *(const bf16x8*)&Bt[wc*64 + ni*16 + l15][ko];
#pragma unroll
                for (int mi = 0; mi < 4; ++mi)
#pragma unroll
                    for (int ni = 0; ni < 4; ++ni)
                        acc[mi][ni] = __builtin_amdgcn_mfma_f32_16x16x32_bf16(
                            af[mi], bfr[ni], acc[mi][ni], 0, 0, 0);
            }
        }

#pragma unroll
        for (int mi = 0; mi < 4; ++mi)
#pragma unroll
            for (int r = 0; r < 4; ++r) {
                const int row_g = row0 + wr*64 + mi*16 + lhi*4 + r;
#pragma unroll
                for (int ni = 0; ni < 4; ++ni) {
                    const int col_g = colt0 + wc*64 + ni*16 + l15;
                    if (row_g == col_g) numer[row_g] = acc[mi][ni][r];
                }
                const int idx = mi * 4 + r;
                const float v0 = acc[mi][0][r], v1 = acc[mi][1][r];
                const float v2 = acc[mi][2][r], v3 = acc[mi][3][r];
                const float mx = fmaxf(fmaxf(v0, v1), fmaxf(v2, v3));
                const float mn = fmaxf(m_run[idx], mx);
                const float scale = __expf(m_run[idx] - mn);
                s_run[idx] = s_run[idx] * scale
                           + __expf(v0 - mn) + __expf(v1 - mn)
                           + __expf(v2 - mn) + __expf(v3 - mn);
                m_run[idx] = mn;
            }
    }

#pragma unroll
    for (int idx = 0; idx < 16; ++idx) {
        float m = m_run[idx], s = s_run[idx];
#pragma unroll
        for (int off = 1; off < 16; off <<= 1) {
            const float mo = __shfl_xor(m, off, 64);
            const float so = __shfl_xor(s, off, 64);
            const float mn = fmaxf(m, mo);
            s = s * __expf(m - mn) + so * __expf(mo - mn);
            m = mn;
        }
        m_run[idx] = m; s_run[idx] = s;
    }

    if (l15 == 0) {
        const int slot = cs * 2 + wc;
#pragma unroll
        for (int mi = 0; mi < 4; ++mi)
#pragma unroll
            for (int r = 0; r < 4; ++r) {
                const int row_g = row0 + wr*64 + mi*16 + lhi*4 + r;
                pm[row_g * NPART_FB + slot] = m_run[mi*4 + r];
                ps[row_g * NPART_FB + slot] = s_run[mi*4 + r];
            }
    }
}

extern "C" void kernel_launch(void* const* d_in, const int* in_sizes, int n_in,
                              void* d_out, int out_size, void* d_ws, size_t ws_size,
                              hipStream_t stream) {
    (void)in_sizes; (void)n_in; (void)out_size;
    const float* x   = (const float*)d_in[0];
    const float* emb = (const float*)d_in[1];
    const int*   tgt = (const int*)d_in[2];
    float* out = (float*)d_out;

    const size_t elems = (size_t)N_TOK * D_DIM;
    const size_t need  = elems * 2
                       + (size_t)N_TOK * 4
                       + (size_t)N_TOK * NPART * 4 * 2
                       + FIN_BLOCKS * 8;

    if (ws_size >= need) {
        unsigned char* xb8 = (unsigned char*)d_ws;
        unsigned char* eb8 = xb8 + elems;
        float* numer = (float*)(eb8 + elems);
        float* pm    = numer + N_TOK;
        float* ps    = pm + (size_t)N_TOK * NPART;
        float* bl    = ps + (size_t)N_TOK * NPART;
        float* bc    = bl + FIN_BLOCKS;

        conv_fp8_frag<<<1024, 256, 0, stream>>>(x, emb, xb8, eb8);
        nce_gemm_mx<<<NSL3 * NSL3, 256, 0, stream>>>(xb8, eb8, numer, pm, ps);
        nce_finish_a<<<FIN_BLOCKS, 256, 0, stream>>>(tgt, numer, pm, ps, bl, bc, NPART);
        nce_finish_b<<<1, 256, 0, stream>>>(bl, bc, out, FIN_BLOCKS);
    } else {
        float* numer = (float*)d_ws;
        float* pm    = numer + N_TOK;
        float* ps    = pm + (size_t)N_TOK * NPART_FB;
        float* bl    = ps + (size_t)N_TOK * NPART_FB;
        float* bc    = bl + FIN_BLOCKS;
        nce_gemm_fb<<<dim3(N_TOK / BM, NSLICE_FB), 256, 0, stream>>>(x, emb, numer, pm, ps);
        nce_finish_a<<<FIN_BLOCKS, 256, 0, stream>>>(tgt, numer, pm, ps, bl, bc, NPART_FB);
        nce_finish_b<<<1, 256, 0, stream>>>(bl, bc, out, FIN_BLOCKS);
    }
}